// Round 25
// baseline (244.805 us; speedup 1.0000x reference)
//
#include <hip/hip_runtime.h>

#define Hc 96
#define Wc 96
#define Cc 256
#define Bc 4
#define KK 9
#define HW 9216          // Hc*Wc
#define PIX 36864        // Bc*HW
#define CK 2304          // Cc*KK

typedef _Float16 f16;
typedef __attribute__((ext_vector_type(4))) _Float16 f16x4;
typedef __attribute__((ext_vector_type(8))) _Float16 f16x8;
typedef __attribute__((ext_vector_type(4))) float f32x4;

__device__ __forceinline__ int clampi(int v, int lo, int hi) {
    return v < lo ? lo : (v > hi ? hi : v);
}

#define SB() __builtin_amdgcn_sched_barrier(0)

// ---------- merged prep: NCHW->NHWC f16 (blocks 0..2303) + all-layer weight
// transpose (blocks 2304..10079) in ONE launch ----------
__global__ __launch_bounds__(256) void prep_all_kernel(
    const float* __restrict__ x0,
    const float* __restrict__ w0, const float* __restrict__ wo0,
    const float* __restrict__ w1, const float* __restrict__ wo1,
    const float* __restrict__ w2, const float* __restrict__ wo2,
    f16* __restrict__ x16, f16* __restrict__ wT2, f16* __restrict__ woffT)
{
    const int blk = blockIdx.x;
    const int tid = threadIdx.x;
    if (blk < 2304) {
        __shared__ float st[64][65];
        const int hw0 = (blk % 144) * 64;
        const int c0  = ((blk / 144) & 3) * 64;
        const int b   = blk / 576;
        const int a = tid & 63, r = tid >> 6;
#pragma unroll
        for (int it = 0; it < 16; ++it) {
            int cl = it * 4 + r;
            st[cl][a] = x0[((size_t)(b * Cc + c0 + cl)) * HW + hw0 + a];
        }
        __syncthreads();
#pragma unroll
        for (int it = 0; it < 16; ++it) {
            int hwl = it * 4 + r;
            x16[((size_t)(b * HW + hw0 + hwl)) * Cc + c0 + a] = (f16)st[a][hwl];
        }
    } else {
        const int bb = blk - 2304;
        const int l = bb / 2592, b = bb - l * 2592;
        const float* w = (l == 0) ? w0 : (l == 1) ? w1 : w2;
        const float* wo = (l == 0) ? wo0 : (l == 1) ? wo1 : wo2;
        if (b < 2304) {
            int u = b * 256 + tid;            // < 589824
            int c = u & 255, o = (u >> 8) & 255, k = u >> 16;
            wT2[(size_t)l * CK * Cc + u] = (f16)w[(o * Cc + c) * KK + k];
        } else {
            int u = (b - 2304) * 256 + tid;   // < 73728
            int c = u & 255, j = (u >> 8) & 31, k = u >> 13;
            float v = (j < 18) ? wo[((size_t)j * Cc + c) * KK + k] : 0.f;
            woffT[(size_t)l * 9 * 32 * Cc + u] = (f16)v;
        }
    }
}

// FUSED: offset-conv (phase A) + deformable sampling + GEMM + ReLU (phase B).
// Block: 768 threads (12 waves), 256 out x 144 pix. Grid = 256 = 1 block/CU.
// R25: weight RING-3 — W issued TWO chunks ahead (read buf g%3, write
// (g+2)%3). Samplers need NO end-of-chunk vmcnt: their blend at chunk g
// waits C issued at g-1 (after W_{g+1}) -> in-order retirement covers the
// W needed at g+1. Waves 9-11: vmcnt(4) covers a full chunk. Tap tables
// shrunk (s_id ushort4, s_wt f16x4 — blend already casts to f16, so
// arithmetic is bit-identical) and phase-A s_a aliased onto s_w[2] to fit
// the third buffer: LDS 152.25KB <= 160.
__global__ __launch_bounds__(768, 3) void fused_layer_kernel(
    const f16* __restrict__ x16, const f16* __restrict__ wT2,
    const f16* __restrict__ woffT, const float* __restrict__ b_off,
    f16* __restrict__ o16, float* __restrict__ oN, int last)
{
    __shared__ __align__(16) f16 s_w[3][2][8192];  // 96KB ring [buf][half][256o x 32c swz]
    __shared__ __align__(16) f16 s_s[2][2][4608];  // 36KB [buf][half][144p x 32c swz]
    __shared__ ushort4 s_id[9][144];               // 10.125KB
    __shared__ __align__(8) f16x4 s_wt[9][144];    // 10.125KB

    const int bid = blockIdx.x;
    const int swz = (bid & 7) * 32 + (bid >> 3); // 256 blocks, XCD-chunked
    const int p0 = swz * 144;                    // no image straddle
    const int imgb = (p0 / HW) * HW;
    const int tid = threadIdx.x, lane = tid & 63, wid = tid >> 6;
    const int wo = wid & 3, wp = wid >> 2;
    const bool sampler = (wid < 9);              // tids 0..575 <=> ps 0..143
    const int ps = tid >> 2, cg = tid & 3;
    const int qa = ((lane >> 4) ^ ((lane >> 1) & 3)) * 8;
    const int qs = (cg ^ ((ps >> 1) & 3)) * 8;
    const f16* xb = x16 + (size_t)imgb * Cc;
    const int wlo = (tid >> 2) * Cc + ((tid & 3) ^ ((tid >> 3) & 3)) * 8;
    const int wds = tid * 8;
    // sampler pixel coords (valid for tid<576)
    const int hwp = p0 + ps - imgb;
    const int hp = hwp / Wc, wp_ = hwp - hp * Wc;
    // phase-A A-stage mapping (tids 576..767; tids 576..639 take a 2nd slot)
    const int au0 = tid - 576;
    const int arow0 = au0 >> 3, acb0 = au0 & 7;
    const int ah0 = acb0 >> 2, aq0 = acb0 & 3;
    const int adst0 = arow0 * 32 + ((aq0 ^ ((arow0 >> 1) & 3)) * 8);
    const int arow1 = arow0 + 24;
    const int adst1 = arow1 * 32 + ((aq0 ^ ((arow1 >> 1) & 3)) * 8);
    // phase-A A staging aliased onto the (phase-A-unused) s_w[2] region
    f16 (*s_a)[2][1024] = reinterpret_cast<f16(*)[2][1024]>(&s_w[2][0][0]);

    // ================= PHASE A: offset conv =================
    {
        f32x4 accA[2];
        accA[0] = (f32x4){0.f, 0.f, 0.f, 0.f};
        accA[1] = (f32x4){0.f, 0.f, 0.f, 0.f};
        f16x8 X0, X1;           // single reg pipeline buffer (stage->reissue)

#define PA_LOAD(q) do {                                                        \
    int q_ = (q) > 35 ? 35 : (q);                                              \
    int k2_ = q_ >> 2, cq_ = q_ & 3;                                           \
    int ky_ = k2_ / 3, kx_ = k2_ - ky_ * 3;                                    \
    if (sampler) {                                                             \
        int yy_ = hp + ky_ - 1, xx_ = wp_ + kx_ - 1;                           \
        f16x8 t0_ = {0,0,0,0,0,0,0,0}, t1_ = {0,0,0,0,0,0,0,0};                \
        if (yy_ >= 0 && yy_ < Hc && xx_ >= 0 && xx_ < Wc) {                    \
            const f16* s_ = x16 + ((size_t)(imgb + yy_ * Wc + xx_)) * Cc + cq_ * 64 + cg * 8; \
            t0_ = *(const f16x8*)s_;                                           \
            t1_ = *(const f16x8*)(s_ + 32);                                    \
        }                                                                      \
        X0 = t0_; X1 = t1_;                                                    \
    } else {                                                                   \
        X0 = *(const f16x8*)(woffT + ((size_t)(k2_ * 32 + arow0)) * Cc + cq_ * 64 + acb0 * 8); \
        if (tid < 640)                                                         \
            X1 = *(const f16x8*)(woffT + ((size_t)(k2_ * 32 + arow1)) * Cc + cq_ * 64 + acb0 * 8); \
    }                                                                          \
} while (0)

#define PA_STAGE(nb) do {                                                      \
    if (sampler) {                                                             \
        *(f16x8*)&s_s[nb][0][ps * 32 + qs] = X0;                               \
        *(f16x8*)&s_s[nb][1][ps * 32 + qs] = X1;                               \
    } else {                                                                   \
        *(f16x8*)&s_a[nb][ah0][adst0] = X0;                                    \
        if (tid < 640) *(f16x8*)&s_a[nb][ah0][adst1] = X1;                     \
    }                                                                          \
} while (0)

        PA_LOAD(0);
        PA_STAGE(0);                       // waits phase-0 loads
        PA_LOAD(1);                        // reissue: phase 1 in flight
        asm volatile("s_waitcnt lgkmcnt(0)" ::: "memory"); SB();
        __builtin_amdgcn_s_barrier(); SB();

        for (int p = 0; p < 36; ++p) {
            const int bb = p & 1, nb = bb ^ 1;
            f16x8 af0, af1, bf0, bf1;
            if (sampler) {
                af0 = *(const f16x8*)&s_a[bb][0][((lane & 15)) * 32 + qa];
                af1 = *(const f16x8*)&s_a[bb][0][((16 + (lane & 15))) * 32 + qa];
                bf0 = *(const f16x8*)&s_s[bb][0][(wid * 16 + (lane & 15)) * 32 + qa];
            }
            // stage X (holds p+1, loaded one full phase ago), reload for p+2
            PA_STAGE(nb);
            PA_LOAD(p + 2);
            if (sampler) {
                accA[0] = __builtin_amdgcn_mfma_f32_16x16x32_f16(af0, bf0, accA[0], 0, 0, 0);
                accA[1] = __builtin_amdgcn_mfma_f32_16x16x32_f16(af1, bf0, accA[1], 0, 0, 0);
                af0 = *(const f16x8*)&s_a[bb][1][((lane & 15)) * 32 + qa];
                af1 = *(const f16x8*)&s_a[bb][1][((16 + (lane & 15))) * 32 + qa];
                bf1 = *(const f16x8*)&s_s[bb][1][(wid * 16 + (lane & 15)) * 32 + qa];
                accA[0] = __builtin_amdgcn_mfma_f32_16x16x32_f16(af0, bf1, accA[0], 0, 0, 0);
                accA[1] = __builtin_amdgcn_mfma_f32_16x16x32_f16(af1, bf1, accA[1], 0, 0, 0);
            }
            asm volatile("s_waitcnt lgkmcnt(0)" ::: "memory"); SB();
            __builtin_amdgcn_s_barrier(); SB();
        }

        // epilogue A: rows 4q..4q+3 -> taps 2q,2q+1 ; rows 16,17 (q==0) -> tap 8
        if (sampler) {
            const int q = lane >> 4;
            const int pxl = wid * 16 + (lane & 15);
            const int hwq = p0 + pxl - imgb;
            const int hq = hwq / Wc, wq = hwq - hq * Wc;
#define STORE_TAP_LDS(kk, offy, offx) do {                                     \
    float py_ = (float)(hq - 1 + (kk) / 3) + (offy);                           \
    float px_ = (float)(wq - 1 + (kk) % 3) + (offx);                           \
    float y0f_ = floorf(py_), x0f_ = floorf(px_);                              \
    float wy_ = py_ - y0f_, wx_ = px_ - x0f_;                                  \
    int iy0_ = (int)y0f_, ix0_ = (int)x0f_;                                    \
    float vy0_ = (y0f_ >= 0.f && y0f_ <= 95.f) ? 1.f : 0.f;                    \
    float vy1_ = (y0f_ + 1.f >= 0.f && y0f_ + 1.f <= 95.f) ? 1.f : 0.f;        \
    float vx0_ = (x0f_ >= 0.f && x0f_ <= 95.f) ? 1.f : 0.f;                    \
    float vx1_ = (x0f_ + 1.f >= 0.f && x0f_ + 1.f <= 95.f) ? 1.f : 0.f;        \
    int cy0_ = clampi(iy0_, 0, 95), cy1_ = clampi(iy0_ + 1, 0, 95);            \
    int cx0_ = clampi(ix0_, 0, 95), cx1_ = clampi(ix0_ + 1, 0, 95);            \
    s_id[kk][pxl] = make_ushort4((unsigned short)(cy0_ * Wc + cx0_),           \
                                 (unsigned short)(cy0_ * Wc + cx1_),           \
                                 (unsigned short)(cy1_ * Wc + cx0_),           \
                                 (unsigned short)(cy1_ * Wc + cx1_));          \
    f16x4 wv4_;                                                                \
    wv4_[0] = (f16)((1.f - wy_) * (1.f - wx_) * vy0_ * vx0_);                  \
    wv4_[1] = (f16)((1.f - wy_) * wx_ * vy0_ * vx1_);                          \
    wv4_[2] = (f16)(wy_ * (1.f - wx_) * vy1_ * vx0_);                          \
    wv4_[3] = (f16)(wy_ * wx_ * vy1_ * vx1_);                                  \
    s_wt[kk][pxl] = wv4_;                                                      \
} while (0)
            STORE_TAP_LDS(2 * q,     accA[0][0] + b_off[4 * q],
                                     accA[0][1] + b_off[4 * q + 1]);
            STORE_TAP_LDS(2 * q + 1, accA[0][2] + b_off[4 * q + 2],
                                     accA[0][3] + b_off[4 * q + 3]);
            if (q == 0)
                STORE_TAP_LDS(8, accA[1][0] + b_off[16], accA[1][1] + b_off[17]);
#undef STORE_TAP_LDS
        }
        asm volatile("s_waitcnt lgkmcnt(0)" ::: "memory"); SB();
        __builtin_amdgcn_s_barrier(); SB();
    }

    // ================= PHASE B: deform, ring-3 weights =================
#define ISSUE_W(kt, cq, wb) do {                                               \
    const f16* g0_ = wT2 + wlo + ((size_t)((kt) * 256)) * Cc + (cq) * 64;      \
    __builtin_amdgcn_global_load_lds(                                          \
        (const __attribute__((address_space(1))) void*)g0_,                    \
        (__attribute__((address_space(3))) void*)&s_w[wb][0][wds], 16, 0, 0);  \
    __builtin_amdgcn_global_load_lds(                                          \
        (const __attribute__((address_space(1))) void*)(g0_ + 32),             \
        (__attribute__((address_space(3))) void*)&s_w[wb][1][wds], 16, 0, 0);  \
    if (wid >= 8) {                                                            \
        const f16* g1_ = g0_ + (size_t)64 * Cc;                                \
        __builtin_amdgcn_global_load_lds(                                      \
            (const __attribute__((address_space(1))) void*)g1_,                \
            (__attribute__((address_space(3))) void*)&s_w[wb][0][2048 + wds], 16, 0, 0); \
        __builtin_amdgcn_global_load_lds(                                      \
            (const __attribute__((address_space(1))) void*)(g1_ + 32),         \
            (__attribute__((address_space(3))) void*)&s_w[wb][1][2048 + wds], 16, 0, 0); \
    }                                                                          \
} while (0)

#define ISSUE_C(dst, idv, co) do {                                             \
    (dst)[0] = *(const f16x8*)(xb + (size_t)(idv).x * Cc + (co) + cg * 8);     \
    (dst)[1] = *(const f16x8*)(xb + (size_t)(idv).y * Cc + (co) + cg * 8);     \
    (dst)[2] = *(const f16x8*)(xb + (size_t)(idv).z * Cc + (co) + cg * 8);     \
    (dst)[3] = *(const f16x8*)(xb + (size_t)(idv).w * Cc + (co) + cg * 8);     \
} while (0)

#define BLEND_WRITE(src, wvv, h, nb) do {                                      \
    f16x8 sv_ = (src)[0] * (wvv)[0] + (src)[1] * (wvv)[1]                      \
              + (src)[2] * (wvv)[2] + (src)[3] * (wvv)[3];                     \
    *(f16x8*)&s_s[nb][h][ps * 32 + qs] = sv_;                                  \
} while (0)

    f32x4 acc[4][3];
#pragma unroll
    for (int mi = 0; mi < 4; ++mi)
#pragma unroll
        for (int ni = 0; ni < 3; ++ni) acc[mi][ni] = (f32x4){0.f, 0.f, 0.f, 0.f};

    f16x8 c4a[4], c4b[4];
    ushort4 id;
    f16x4 wv;
    ushort4 idN;
    f16x4 wvN;
    if (sampler) {
        id = s_id[0][ps];
        wv = s_wt[0][ps];
    }

    // prologue: W(g=0)->buf0, W(g=1)->buf1; samplers fill s_s[0] from C(0)
    // and leave C(1) x8 in flight (their blend wait covers W in-order);
    // waves 9-11 drain W0 via vmcnt(4) (W1 stays in flight).
    ISSUE_W(0, 0, 0);
    ISSUE_W(0, 1, 1);
    SB();
    if (sampler) {
        ISSUE_C(c4a, id, 0);
        ISSUE_C(c4b, id, 32);
        BLEND_WRITE(c4a, wv, 0, 0);        // waits C(0) -> retires W0,W1
        BLEND_WRITE(c4b, wv, 1, 0);
        ISSUE_C(c4a, id, 64);
        ISSUE_C(c4b, id, 96);
        asm volatile("s_waitcnt lgkmcnt(0)" ::: "memory"); SB();
    } else {
        asm volatile("s_waitcnt vmcnt(4)" ::: "memory"); SB();
    }
    __builtin_amdgcn_s_barrier(); SB();

    int rb = 0;                            // read buffer = g % 3
    for (int k = 0; k < 9; ++k) {
#pragma unroll
        for (int ch = 0; ch < 4; ++ch) {
            const int g = k * 4 + ch;
            const int bb = g & 1, nb = bb ^ 1;
            const int g2 = (g + 2 > 35) ? 35 : g + 2;
            const int wb = (rb + 2 >= 3) ? rb - 1 : rb + 2;   // (g+2)%3
            f16x8 bf0[3], bf1[3];
#pragma unroll
            for (int ni = 0; ni < 3; ++ni) {
                bf0[ni] = *(const f16x8*)&s_w[rb][0][0];      // placeholder (overwritten)
            }
#pragma unroll
            for (int ni = 0; ni < 3; ++ni) {
                bf0[ni] = *(const f16x8*)&s_s[bb][0][(wp * 48 + ni * 16 + (lane & 15)) * 32 + qa];
                bf1[ni] = *(const f16x8*)&s_s[bb][1][(wp * 48 + ni * 16 + (lane & 15)) * 32 + qa];
            }
            if (sampler) {
                if (ch == 1) {             // LDS read; needed from ch2
                    const int kn = (k < 8) ? k + 1 : 8;
                    idN = s_id[kn][ps];
                    wvN = s_wt[kn][ps];
                }
                ISSUE_W(g2 >> 2, g2 & 3, wb);
                SB();
                {
                    const f16x4 wvu = (ch == 3) ? wvN : wv;
                    const ushort4 idu = (ch >= 2) ? idN : id;
                    const int co2 = ((ch + 2) & 3) * 64;
                    BLEND_WRITE(c4a, wvu, 0, nb);
                    ISSUE_C(c4a, idu, co2);
                    BLEND_WRITE(c4b, wvu, 1, nb);
                    ISSUE_C(c4b, idu, co2 + 32);
                }
            } else {
                ISSUE_W(g2 >> 2, g2 & 3, wb);
                SB();
            }
#pragma unroll
            for (int mi = 0; mi < 4; ++mi) {
                f16x8 af = *(const f16x8*)&s_w[rb][0][(wo * 64 + mi * 16 + (lane & 15)) * 32 + qa];
#pragma unroll
                for (int ni = 0; ni < 3; ++ni)
                    acc[mi][ni] = __builtin_amdgcn_mfma_f32_16x16x32_f16(
                        af, bf0[ni], acc[mi][ni], 0, 0, 0);
            }
#pragma unroll
            for (int mi = 0; mi < 4; ++mi) {
                f16x8 af = *(const f16x8*)&s_w[rb][1][(wo * 64 + mi * 16 + (lane & 15)) * 32 + qa];
#pragma unroll
                for (int ni = 0; ni < 3; ++ni)
                    acc[mi][ni] = __builtin_amdgcn_mfma_f32_16x16x32_f16(
                        af, bf1[ni], acc[mi][ni], 0, 0, 0);
            }
            // RACE-FREE POINT: ds_writes drained (lgkm). Samplers: W needed
            // next chunk already retired by this chunk's blend wait (in-order,
            // C issued after it last chunk). Waves 9-11: vmcnt(4) retires
            // W_{g+1} (issued last chunk), leaves W_{g+2} in flight.
            asm volatile("s_waitcnt lgkmcnt(0)" ::: "memory"); SB();
            if (!sampler) {
                asm volatile("s_waitcnt vmcnt(4)" ::: "memory"); SB();
            }
            __builtin_amdgcn_s_barrier(); SB();
            rb = (rb + 1 >= 3) ? 0 : rb + 1;
        }
        if (sampler) { id = idN; wv = wvN; }
    }

    // epilogue: ReLU; D row = output = (lane>>4)*4+j, col = pixel = lane&15
    if (!last) {
#pragma unroll
        for (int ni = 0; ni < 3; ++ni) {
            const int p = p0 + wp * 48 + ni * 16 + (lane & 15);
#pragma unroll
            for (int mi = 0; mi < 4; ++mi) {
                const int o0 = wo * 64 + mi * 16 + (lane >> 4) * 4;
                f32x4 v = acc[mi][ni];
                f16x4 h = {(f16)fmaxf(v[0], 0.f), (f16)fmaxf(v[1], 0.f),
                           (f16)fmaxf(v[2], 0.f), (f16)fmaxf(v[3], 0.f)};
                *(f16x4*)&o16[(size_t)p * Cc + o0] = h;
            }
        }
    } else {
        const int bimg = imgb / HW;
#pragma unroll
        for (int ni = 0; ni < 3; ++ni) {
            const int p = p0 + wp * 48 + ni * 16 + (lane & 15);
            const int hwl = p - imgb;
#pragma unroll
            for (int mi = 0; mi < 4; ++mi) {
                const int o0 = wo * 64 + mi * 16 + (lane >> 4) * 4;
#pragma unroll
                for (int j = 0; j < 4; ++j)
                    oN[((size_t)(bimg * Cc + o0 + j)) * HW + hwl] =
                        fmaxf(acc[mi][ni][j], 0.f);
            }
        }
    }
#undef ISSUE_W
#undef ISSUE_C
#undef BLEND_WRITE
#undef PA_LOAD
#undef PA_STAGE
}

extern "C" void kernel_launch(void* const* d_in, const int* in_sizes, int n_in,
                              void* d_out, int out_size, void* d_ws, size_t ws_size,
                              hipStream_t stream)
{
    const float* x0 = (const float*)d_in[0];
    float* out = (float*)d_out;

    f16*   x16a = (f16*)d_ws;                          // PIX*Cc f16
    f16*   x16b = x16a + (size_t)PIX * Cc;             // PIX*Cc f16
    f16*   wT2  = x16b + (size_t)PIX * Cc;             // 3 * CK*Cc f16
    f16*   woffT = wT2 + (size_t)3 * CK * Cc;          // 3 * 9*32*256 f16

    prep_all_kernel<<<2304 + 3 * 2592, 256, 0, stream>>>(
        x0,
        (const float*)d_in[3], (const float*)d_in[1],
        (const float*)d_in[6], (const float*)d_in[4],
        (const float*)d_in[9], (const float*)d_in[7],
        x16a, wT2, woffT);

    const f16* xin = x16a;
    for (int L = 0; L < 3; ++L) {
        const float* b_off = (const float*)d_in[2 + 3 * L];
        const int last = (L == 2);
        f16* xo = (L == 0) ? x16b : x16a;

        fused_layer_kernel<<<PIX / 144, 768, 0, stream>>>(
            xin, wT2 + (size_t)L * CK * Cc, woffT + (size_t)L * 9 * 32 * Cc,
            b_off, xo, out, last);

        xin = xo;
    }
}

// Round 26
// 243.469 us; speedup vs baseline: 1.0055x; 1.0055x over previous
//
#include <hip/hip_runtime.h>

#define Hc 96
#define Wc 96
#define Cc 256
#define Bc 4
#define KK 9
#define HW 9216          // Hc*Wc
#define PIX 36864        // Bc*HW
#define CK 2304          // Cc*KK

typedef _Float16 f16;
typedef __attribute__((ext_vector_type(4))) _Float16 f16x4;
typedef __attribute__((ext_vector_type(8))) _Float16 f16x8;
typedef __attribute__((ext_vector_type(4))) float f32x4;

__device__ __forceinline__ int clampi(int v, int lo, int hi) {
    return v < lo ? lo : (v > hi ? hi : v);
}

#define SB() __builtin_amdgcn_sched_barrier(0)

// ---------- merged prep: NCHW->NHWC f16 (blocks 0..2303) + all-layer weight
// transpose (blocks 2304..10079) in ONE launch ----------
__global__ __launch_bounds__(256) void prep_all_kernel(
    const float* __restrict__ x0,
    const float* __restrict__ w0, const float* __restrict__ wo0,
    const float* __restrict__ w1, const float* __restrict__ wo1,
    const float* __restrict__ w2, const float* __restrict__ wo2,
    f16* __restrict__ x16, f16* __restrict__ wT2, f16* __restrict__ woffT)
{
    const int blk = blockIdx.x;
    const int tid = threadIdx.x;
    if (blk < 2304) {
        __shared__ float st[64][65];
        const int hw0 = (blk % 144) * 64;
        const int c0  = ((blk / 144) & 3) * 64;
        const int b   = blk / 576;
        const int a = tid & 63, r = tid >> 6;
#pragma unroll
        for (int it = 0; it < 16; ++it) {
            int cl = it * 4 + r;
            st[cl][a] = x0[((size_t)(b * Cc + c0 + cl)) * HW + hw0 + a];
        }
        __syncthreads();
#pragma unroll
        for (int it = 0; it < 16; ++it) {
            int hwl = it * 4 + r;
            x16[((size_t)(b * HW + hw0 + hwl)) * Cc + c0 + a] = (f16)st[a][hwl];
        }
    } else {
        const int bb = blk - 2304;
        const int l = bb / 2592, b = bb - l * 2592;
        const float* w = (l == 0) ? w0 : (l == 1) ? w1 : w2;
        const float* wo = (l == 0) ? wo0 : (l == 1) ? wo1 : wo2;
        if (b < 2304) {
            int u = b * 256 + tid;            // < 589824
            int c = u & 255, o = (u >> 8) & 255, k = u >> 16;
            wT2[(size_t)l * CK * Cc + u] = (f16)w[(o * Cc + c) * KK + k];
        } else {
            int u = (b - 2304) * 256 + tid;   // < 73728
            int c = u & 255, j = (u >> 8) & 31, k = u >> 13;
            float v = (j < 18) ? wo[((size_t)j * Cc + c) * KK + k] : 0.f;
            woffT[(size_t)l * 9 * 32 * Cc + u] = (f16)v;
        }
    }
}

// FUSED: offset-conv (phase A) + deformable sampling + GEMM + ReLU (phase B).
// Block: 768 threads (12 waves), 256 out x 144 pix. Grid = 256 = 1 block/CU.
// R26: ring-3 weights with ALL-STATIC ring indices — phase B is kj(3) x
// fully-unrolled u(12); 12 = 0 mod 3 and mod 4, so rb=u%3, wb=(u+2)%3,
// bb=u&1 are compile-time (R25's runtime rb forced per-access LDS address
// arithmetic and regressed). Samplers: NO end-of-chunk vmcnt (blend's
// counted wait at chunk g retires W_{g+1} in-order, since W_{g+1} was
// issued before the corners the blend waits on). Waves 9-11: vmcnt(4).
__global__ __launch_bounds__(768, 3) void fused_layer_kernel(
    const f16* __restrict__ x16, const f16* __restrict__ wT2,
    const f16* __restrict__ woffT, const float* __restrict__ b_off,
    f16* __restrict__ o16, float* __restrict__ oN, int last)
{
    __shared__ __align__(16) f16 s_w[3][2][8192];  // 96KB ring [buf][half][256o x 32c swz]
    __shared__ __align__(16) f16 s_s[2][2][4608];  // 36KB [buf][half][144p x 32c swz]
    __shared__ ushort4 s_id[9][144];               // 10.125KB
    __shared__ __align__(8) f16x4 s_wt[9][144];    // 10.125KB

    const int bid = blockIdx.x;
    const int swz = (bid & 7) * 32 + (bid >> 3); // 256 blocks, XCD-chunked
    const int p0 = swz * 144;                    // no image straddle
    const int imgb = (p0 / HW) * HW;
    const int tid = threadIdx.x, lane = tid & 63, wid = tid >> 6;
    const int wo = wid & 3, wp = wid >> 2;
    const bool sampler = (wid < 9);              // tids 0..575 <=> ps 0..143
    const int ps = tid >> 2, cg = tid & 3;
    const int qa = ((lane >> 4) ^ ((lane >> 1) & 3)) * 8;
    const int qs = (cg ^ ((ps >> 1) & 3)) * 8;
    const f16* xb = x16 + (size_t)imgb * Cc;
    const int wlo = (tid >> 2) * Cc + ((tid & 3) ^ ((tid >> 3) & 3)) * 8;
    const int wds = tid * 8;
    // sampler pixel coords (valid for tid<576)
    const int hwp = p0 + ps - imgb;
    const int hp = hwp / Wc, wp_ = hwp - hp * Wc;
    // phase-A A-stage mapping (tids 576..767; tids 576..639 take a 2nd slot)
    const int au0 = tid - 576;
    const int arow0 = au0 >> 3, acb0 = au0 & 7;
    const int ah0 = acb0 >> 2, aq0 = acb0 & 3;
    const int adst0 = arow0 * 32 + ((aq0 ^ ((arow0 >> 1) & 3)) * 8);
    const int arow1 = arow0 + 24;
    const int adst1 = arow1 * 32 + ((aq0 ^ ((arow1 >> 1) & 3)) * 8);
    // phase-A A staging aliased onto the (phase-A-unused) s_w[2] region
    f16 (*s_a)[2][1024] = reinterpret_cast<f16(*)[2][1024]>(&s_w[2][0][0]);

    // ================= PHASE A: offset conv =================
    {
        f32x4 accA[2];
        accA[0] = (f32x4){0.f, 0.f, 0.f, 0.f};
        accA[1] = (f32x4){0.f, 0.f, 0.f, 0.f};
        f16x8 X0, X1;           // single reg pipeline buffer (stage->reissue)

#define PA_LOAD(q) do {                                                        \
    int q_ = (q) > 35 ? 35 : (q);                                              \
    int k2_ = q_ >> 2, cq_ = q_ & 3;                                           \
    int ky_ = k2_ / 3, kx_ = k2_ - ky_ * 3;                                    \
    if (sampler) {                                                             \
        int yy_ = hp + ky_ - 1, xx_ = wp_ + kx_ - 1;                           \
        f16x8 t0_ = {0,0,0,0,0,0,0,0}, t1_ = {0,0,0,0,0,0,0,0};                \
        if (yy_ >= 0 && yy_ < Hc && xx_ >= 0 && xx_ < Wc) {                    \
            const f16* s_ = x16 + ((size_t)(imgb + yy_ * Wc + xx_)) * Cc + cq_ * 64 + cg * 8; \
            t0_ = *(const f16x8*)s_;                                           \
            t1_ = *(const f16x8*)(s_ + 32);                                    \
        }                                                                      \
        X0 = t0_; X1 = t1_;                                                    \
    } else {                                                                   \
        X0 = *(const f16x8*)(woffT + ((size_t)(k2_ * 32 + arow0)) * Cc + cq_ * 64 + acb0 * 8); \
        if (tid < 640)                                                         \
            X1 = *(const f16x8*)(woffT + ((size_t)(k2_ * 32 + arow1)) * Cc + cq_ * 64 + acb0 * 8); \
    }                                                                          \
} while (0)

#define PA_STAGE(nb) do {                                                      \
    if (sampler) {                                                             \
        *(f16x8*)&s_s[nb][0][ps * 32 + qs] = X0;                               \
        *(f16x8*)&s_s[nb][1][ps * 32 + qs] = X1;                               \
    } else {                                                                   \
        *(f16x8*)&s_a[nb][ah0][adst0] = X0;                                    \
        if (tid < 640) *(f16x8*)&s_a[nb][ah0][adst1] = X1;                     \
    }                                                                          \
} while (0)

        PA_LOAD(0);
        PA_STAGE(0);                       // waits phase-0 loads
        PA_LOAD(1);                        // reissue: phase 1 in flight
        asm volatile("s_waitcnt lgkmcnt(0)" ::: "memory"); SB();
        __builtin_amdgcn_s_barrier(); SB();

        for (int p = 0; p < 36; ++p) {
            const int bb = p & 1, nb = bb ^ 1;
            f16x8 af0, af1, bf0, bf1;
            if (sampler) {
                af0 = *(const f16x8*)&s_a[bb][0][((lane & 15)) * 32 + qa];
                af1 = *(const f16x8*)&s_a[bb][0][((16 + (lane & 15))) * 32 + qa];
                bf0 = *(const f16x8*)&s_s[bb][0][(wid * 16 + (lane & 15)) * 32 + qa];
            }
            // stage X (holds p+1, loaded one full phase ago), reload for p+2
            PA_STAGE(nb);
            PA_LOAD(p + 2);
            if (sampler) {
                accA[0] = __builtin_amdgcn_mfma_f32_16x16x32_f16(af0, bf0, accA[0], 0, 0, 0);
                accA[1] = __builtin_amdgcn_mfma_f32_16x16x32_f16(af1, bf0, accA[1], 0, 0, 0);
                af0 = *(const f16x8*)&s_a[bb][1][((lane & 15)) * 32 + qa];
                af1 = *(const f16x8*)&s_a[bb][1][((16 + (lane & 15))) * 32 + qa];
                bf1 = *(const f16x8*)&s_s[bb][1][(wid * 16 + (lane & 15)) * 32 + qa];
                accA[0] = __builtin_amdgcn_mfma_f32_16x16x32_f16(af0, bf1, accA[0], 0, 0, 0);
                accA[1] = __builtin_amdgcn_mfma_f32_16x16x32_f16(af1, bf1, accA[1], 0, 0, 0);
            }
            asm volatile("s_waitcnt lgkmcnt(0)" ::: "memory"); SB();
            __builtin_amdgcn_s_barrier(); SB();
        }

        // epilogue A: rows 4q..4q+3 -> taps 2q,2q+1 ; rows 16,17 (q==0) -> tap 8
        if (sampler) {
            const int q = lane >> 4;
            const int pxl = wid * 16 + (lane & 15);
            const int hwq = p0 + pxl - imgb;
            const int hq = hwq / Wc, wq = hwq - hq * Wc;
#define STORE_TAP_LDS(kk, offy, offx) do {                                     \
    float py_ = (float)(hq - 1 + (kk) / 3) + (offy);                           \
    float px_ = (float)(wq - 1 + (kk) % 3) + (offx);                           \
    float y0f_ = floorf(py_), x0f_ = floorf(px_);                              \
    float wy_ = py_ - y0f_, wx_ = px_ - x0f_;                                  \
    int iy0_ = (int)y0f_, ix0_ = (int)x0f_;                                    \
    float vy0_ = (y0f_ >= 0.f && y0f_ <= 95.f) ? 1.f : 0.f;                    \
    float vy1_ = (y0f_ + 1.f >= 0.f && y0f_ + 1.f <= 95.f) ? 1.f : 0.f;        \
    float vx0_ = (x0f_ >= 0.f && x0f_ <= 95.f) ? 1.f : 0.f;                    \
    float vx1_ = (x0f_ + 1.f >= 0.f && x0f_ + 1.f <= 95.f) ? 1.f : 0.f;        \
    int cy0_ = clampi(iy0_, 0, 95), cy1_ = clampi(iy0_ + 1, 0, 95);            \
    int cx0_ = clampi(ix0_, 0, 95), cx1_ = clampi(ix0_ + 1, 0, 95);            \
    s_id[kk][pxl] = make_ushort4((unsigned short)(cy0_ * Wc + cx0_),           \
                                 (unsigned short)(cy0_ * Wc + cx1_),           \
                                 (unsigned short)(cy1_ * Wc + cx0_),           \
                                 (unsigned short)(cy1_ * Wc + cx1_));          \
    f16x4 wv4_;                                                                \
    wv4_[0] = (f16)((1.f - wy_) * (1.f - wx_) * vy0_ * vx0_);                  \
    wv4_[1] = (f16)((1.f - wy_) * wx_ * vy0_ * vx1_);                          \
    wv4_[2] = (f16)(wy_ * (1.f - wx_) * vy1_ * vx0_);                          \
    wv4_[3] = (f16)(wy_ * wx_ * vy1_ * vx1_);                                  \
    s_wt[kk][pxl] = wv4_;                                                      \
} while (0)
            STORE_TAP_LDS(2 * q,     accA[0][0] + b_off[4 * q],
                                     accA[0][1] + b_off[4 * q + 1]);
            STORE_TAP_LDS(2 * q + 1, accA[0][2] + b_off[4 * q + 2],
                                     accA[0][3] + b_off[4 * q + 3]);
            if (q == 0)
                STORE_TAP_LDS(8, accA[1][0] + b_off[16], accA[1][1] + b_off[17]);
#undef STORE_TAP_LDS
        }
        asm volatile("s_waitcnt lgkmcnt(0)" ::: "memory"); SB();
        __builtin_amdgcn_s_barrier(); SB();
    }

    // ================= PHASE B: deform, ring-3 weights (static indices) ====
#define ISSUE_W(kt, cq, wb) do {                                               \
    const f16* g0_ = wT2 + wlo + ((size_t)((kt) * 256)) * Cc + (cq) * 64;      \
    __builtin_amdgcn_global_load_lds(                                          \
        (const __attribute__((address_space(1))) void*)g0_,                    \
        (__attribute__((address_space(3))) void*)&s_w[wb][0][wds], 16, 0, 0);  \
    __builtin_amdgcn_global_load_lds(                                          \
        (const __attribute__((address_space(1))) void*)(g0_ + 32),             \
        (__attribute__((address_space(3))) void*)&s_w[wb][1][wds], 16, 0, 0);  \
    if (wid >= 8) {                                                            \
        const f16* g1_ = g0_ + (size_t)64 * Cc;                                \
        __builtin_amdgcn_global_load_lds(                                      \
            (const __attribute__((address_space(1))) void*)g1_,                \
            (__attribute__((address_space(3))) void*)&s_w[wb][0][2048 + wds], 16, 0, 0); \
        __builtin_amdgcn_global_load_lds(                                      \
            (const __attribute__((address_space(1))) void*)(g1_ + 32),         \
            (__attribute__((address_space(3))) void*)&s_w[wb][1][2048 + wds], 16, 0, 0); \
    }                                                                          \
} while (0)

#define ISSUE_C(dst, idv, co) do {                                             \
    (dst)[0] = *(const f16x8*)(xb + (size_t)(idv).x * Cc + (co) + cg * 8);     \
    (dst)[1] = *(const f16x8*)(xb + (size_t)(idv).y * Cc + (co) + cg * 8);     \
    (dst)[2] = *(const f16x8*)(xb + (size_t)(idv).z * Cc + (co) + cg * 8);     \
    (dst)[3] = *(const f16x8*)(xb + (size_t)(idv).w * Cc + (co) + cg * 8);     \
} while (0)

#define BLEND_WRITE(src, wvv, h, nb) do {                                      \
    f16x8 sv_ = (src)[0] * (wvv)[0] + (src)[1] * (wvv)[1]                      \
              + (src)[2] * (wvv)[2] + (src)[3] * (wvv)[3];                     \
    *(f16x8*)&s_s[nb][h][ps * 32 + qs] = sv_;                                  \
} while (0)

    f32x4 acc[4][3];
#pragma unroll
    for (int mi = 0; mi < 4; ++mi)
#pragma unroll
        for (int ni = 0; ni < 3; ++ni) acc[mi][ni] = (f32x4){0.f, 0.f, 0.f, 0.f};

    f16x8 c4a[4], c4b[4];
    ushort4 id;
    f16x4 wv;
    ushort4 idN;
    f16x4 wvN;
    if (sampler) {
        id = s_id[0][ps];
        wv = s_wt[0][ps];
    }

    // prologue: W(g=0)->buf0, W(g=1)->buf1; samplers fill s_s[0] from C(0)
    // and leave C(1) x8 in flight (their blend wait covers W in-order);
    // waves 9-11 drain W0 via vmcnt(4) (W1 stays in flight).
    ISSUE_W(0, 0, 0);
    ISSUE_W(0, 1, 1);
    SB();
    if (sampler) {
        ISSUE_C(c4a, id, 0);
        ISSUE_C(c4b, id, 32);
        BLEND_WRITE(c4a, wv, 0, 0);        // waits C(0) -> retires W0,W1
        BLEND_WRITE(c4b, wv, 1, 0);
        ISSUE_C(c4a, id, 64);
        ISSUE_C(c4b, id, 96);
        asm volatile("s_waitcnt lgkmcnt(0)" ::: "memory"); SB();
    } else {
        asm volatile("s_waitcnt vmcnt(4)" ::: "memory"); SB();
    }
    __builtin_amdgcn_s_barrier(); SB();

    for (int kj = 0; kj < 3; ++kj) {
#pragma unroll
        for (int u = 0; u < 12; ++u) {     // g = kj*12 + u; 12%3==0, 12%4==0
            const int bb = u & 1, nb = bb ^ 1;       // static
            const int rb = u % 3;                    // static read buf
            const int wb = (u + 2) % 3;              // static write buf
            f16x8 bf0[3], bf1[3];
#pragma unroll
            for (int ni = 0; ni < 3; ++ni) {
                bf0[ni] = *(const f16x8*)&s_s[bb][0][(wp * 48 + ni * 16 + (lane & 15)) * 32 + qa];
                bf1[ni] = *(const f16x8*)&s_s[bb][1][(wp * 48 + ni * 16 + (lane & 15)) * 32 + qa];
            }
            int g2 = kj * 12 + u + 2;
            if (g2 > 35) g2 = 35;
            if (sampler) {
                if ((u & 3) == 1) {        // tap table read, needed from ch2
                    int kn = kj * 3 + (u >> 2) + 1;
                    if (kn > 8) kn = 8;
                    idN = s_id[kn][ps];
                    wvN = s_wt[kn][ps];
                }
                ISSUE_W(g2 >> 2, g2 & 3, wb);
                SB();                      // pin W before C issue (in-order)
                {
                    const f16x4 wvu = ((u & 3) == 3) ? wvN : wv;
                    const ushort4 idu = ((u & 3) >= 2) ? idN : id;
                    const int co2 = ((u + 2) & 3) * 64;
                    BLEND_WRITE(c4a, wvu, 0, nb);
                    ISSUE_C(c4a, idu, co2);
                    BLEND_WRITE(c4b, wvu, 1, nb);
                    ISSUE_C(c4b, idu, co2 + 32);
                }
            } else {
                ISSUE_W(g2 >> 2, g2 & 3, wb);
                SB();
            }
#pragma unroll
            for (int mi = 0; mi < 4; ++mi) {
                f16x8 af = *(const f16x8*)&s_w[rb][0][(wo * 64 + mi * 16 + (lane & 15)) * 32 + qa];
#pragma unroll
                for (int ni = 0; ni < 3; ++ni)
                    acc[mi][ni] = __builtin_amdgcn_mfma_f32_16x16x32_f16(
                        af, bf0[ni], acc[mi][ni], 0, 0, 0);
            }
#pragma unroll
            for (int mi = 0; mi < 4; ++mi) {
                f16x8 af = *(const f16x8*)&s_w[rb][1][(wo * 64 + mi * 16 + (lane & 15)) * 32 + qa];
#pragma unroll
                for (int ni = 0; ni < 3; ++ni)
                    acc[mi][ni] = __builtin_amdgcn_mfma_f32_16x16x32_f16(
                        af, bf1[ni], acc[mi][ni], 0, 0, 0);
            }
            // RACE-FREE POINT: ds_writes drained (lgkm). Samplers: W for the
            // next chunk already retired by this chunk's blend wait (issued
            // before the corners it waits on). Waves 9-11: vmcnt(4) retires
            // W_{g+1}, leaves W_{g+2} in flight.
            asm volatile("s_waitcnt lgkmcnt(0)" ::: "memory"); SB();
            if (!sampler) {
                asm volatile("s_waitcnt vmcnt(4)" ::: "memory"); SB();
            }
            __builtin_amdgcn_s_barrier(); SB();
            if (sampler && ((u & 3) == 3)) { id = idN; wv = wvN; }
        }
    }

    // epilogue: ReLU; D row = output = (lane>>4)*4+j, col = pixel = lane&15
    if (!last) {
#pragma unroll
        for (int ni = 0; ni < 3; ++ni) {
            const int p = p0 + wp * 48 + ni * 16 + (lane & 15);
#pragma unroll
            for (int mi = 0; mi < 4; ++mi) {
                const int o0 = wo * 64 + mi * 16 + (lane >> 4) * 4;
                f32x4 v = acc[mi][ni];
                f16x4 h = {(f16)fmaxf(v[0], 0.f), (f16)fmaxf(v[1], 0.f),
                           (f16)fmaxf(v[2], 0.f), (f16)fmaxf(v[3], 0.f)};
                *(f16x4*)&o16[(size_t)p * Cc + o0] = h;
            }
        }
    } else {
        const int bimg = imgb / HW;
#pragma unroll
        for (int ni = 0; ni < 3; ++ni) {
            const int p = p0 + wp * 48 + ni * 16 + (lane & 15);
            const int hwl = p - imgb;
#pragma unroll
            for (int mi = 0; mi < 4; ++mi) {
                const int o0 = wo * 64 + mi * 16 + (lane >> 4) * 4;
#pragma unroll
                for (int j = 0; j < 4; ++j)
                    oN[((size_t)(bimg * Cc + o0 + j)) * HW + hwl] =
                        fmaxf(acc[mi][ni][j], 0.f);
            }
        }
    }
#undef ISSUE_W
#undef ISSUE_C
#undef BLEND_WRITE
#undef PA_LOAD
#undef PA_STAGE
}

extern "C" void kernel_launch(void* const* d_in, const int* in_sizes, int n_in,
                              void* d_out, int out_size, void* d_ws, size_t ws_size,
                              hipStream_t stream)
{
    const float* x0 = (const float*)d_in[0];
    float* out = (float*)d_out;

    f16*   x16a = (f16*)d_ws;                          // PIX*Cc f16
    f16*   x16b = x16a + (size_t)PIX * Cc;             // PIX*Cc f16
    f16*   wT2  = x16b + (size_t)PIX * Cc;             // 3 * CK*Cc f16
    f16*   woffT = wT2 + (size_t)3 * CK * Cc;          // 3 * 9*32*256 f16

    prep_all_kernel<<<2304 + 3 * 2592, 256, 0, stream>>>(
        x0,
        (const float*)d_in[3], (const float*)d_in[1],
        (const float*)d_in[6], (const float*)d_in[4],
        (const float*)d_in[9], (const float*)d_in[7],
        x16a, wT2, woffT);

    const f16* xin = x16a;
    for (int L = 0; L < 3; ++L) {
        const float* b_off = (const float*)d_in[2 + 3 * L];
        const int last = (L == 2);
        f16* xo = (L == 0) ? x16b : x16a;

        fused_layer_kernel<<<PIX / 144, 768, 0, stream>>>(
            xin, wT2 + (size_t)L * CK * Cc, woffT + (size_t)L * 9 * 32 * Cc,
            b_off, xo, out, last);

        xin = xo;
    }
}

// Round 27
// 241.601 us; speedup vs baseline: 1.0133x; 1.0077x over previous
//
#include <hip/hip_runtime.h>

#define Hc 96
#define Wc 96
#define Cc 256
#define Bc 4
#define KK 9
#define HW 9216          // Hc*Wc
#define PIX 36864        // Bc*HW
#define CK 2304          // Cc*KK

typedef _Float16 f16;
typedef __attribute__((ext_vector_type(4))) _Float16 f16x4;
typedef __attribute__((ext_vector_type(8))) _Float16 f16x8;
typedef __attribute__((ext_vector_type(4))) float f32x4;

__device__ __forceinline__ int clampi(int v, int lo, int hi) {
    return v < lo ? lo : (v > hi ? hi : v);
}

#define SB() __builtin_amdgcn_sched_barrier(0)

// ---------- merged prep: NCHW->NHWC f16 (blocks 0..2303) + all-layer weight
// transpose (blocks 2304..10079) in ONE launch ----------
__global__ __launch_bounds__(256) void prep_all_kernel(
    const float* __restrict__ x0,
    const float* __restrict__ w0, const float* __restrict__ wo0,
    const float* __restrict__ w1, const float* __restrict__ wo1,
    const float* __restrict__ w2, const float* __restrict__ wo2,
    f16* __restrict__ x16, f16* __restrict__ wT2, f16* __restrict__ woffT)
{
    const int blk = blockIdx.x;
    const int tid = threadIdx.x;
    if (blk < 2304) {
        __shared__ float st[64][65];
        const int hw0 = (blk % 144) * 64;
        const int c0  = ((blk / 144) & 3) * 64;
        const int b   = blk / 576;
        const int a = tid & 63, r = tid >> 6;
#pragma unroll
        for (int it = 0; it < 16; ++it) {
            int cl = it * 4 + r;
            st[cl][a] = x0[((size_t)(b * Cc + c0 + cl)) * HW + hw0 + a];
        }
        __syncthreads();
#pragma unroll
        for (int it = 0; it < 16; ++it) {
            int hwl = it * 4 + r;
            x16[((size_t)(b * HW + hw0 + hwl)) * Cc + c0 + a] = (f16)st[a][hwl];
        }
    } else {
        const int bb = blk - 2304;
        const int l = bb / 2592, b = bb - l * 2592;
        const float* w = (l == 0) ? w0 : (l == 1) ? w1 : w2;
        const float* wo = (l == 0) ? wo0 : (l == 1) ? wo1 : wo2;
        if (b < 2304) {
            int u = b * 256 + tid;            // < 589824
            int c = u & 255, o = (u >> 8) & 255, k = u >> 16;
            wT2[(size_t)l * CK * Cc + u] = (f16)w[(o * Cc + c) * KK + k];
        } else {
            int u = (b - 2304) * 256 + tid;   // < 73728
            int c = u & 255, j = (u >> 8) & 31, k = u >> 13;
            float v = (j < 18) ? wo[((size_t)j * Cc + c) * KK + k] : 0.f;
            woffT[(size_t)l * 9 * 32 * Cc + u] = (f16)v;
        }
    }
}

// FUSED: offset-conv (phase A) + deformable sampling + GEMM + ReLU (phase B).
// Block: 768 threads (12 waves), 256 out x 144 pix. Grid = 256 = 1 block/CU.
// Phase A: SINGLE-buffer stage-then-reissue pipeline (stage X holding p+1,
// loaded a full phase earlier, then reload X for p+2).
// Phase B: R20-proven deform loop; id/wv from LDS (s_id/s_wt). Weight
// double-buffer; race-free drain-own-writes-before-barrier discipline.
// (R24 configuration — ring-3 variants R25/R26 were null/regressive.)
__global__ __launch_bounds__(768, 3) void fused_layer_kernel(
    const f16* __restrict__ x16, const f16* __restrict__ wT2,
    const f16* __restrict__ woffT, const float* __restrict__ b_off,
    f16* __restrict__ o16, float* __restrict__ oN, int last)
{
    __shared__ __align__(16) f16 s_w[2][2][8192];  // 64KB  [buf][half][256o x 32c swz]
    __shared__ __align__(16) f16 s_s[2][2][4608];  // 36KB  [buf][half][144p x 32c swz]
    __shared__ __align__(16) f16 s_a[2][2][1024];  // 8KB   [buf][half][32r x 32c swz]
    __shared__ int4   s_id[9][144];                // 20.25KB
    __shared__ float4 s_wt[9][144];                // 20.25KB

    const int bid = blockIdx.x;
    const int swz = (bid & 7) * 32 + (bid >> 3); // 256 blocks, XCD-chunked
    const int p0 = swz * 144;                    // no image straddle
    const int imgb = (p0 / HW) * HW;
    const int tid = threadIdx.x, lane = tid & 63, wid = tid >> 6;
    const int wo = wid & 3, wp = wid >> 2;
    const bool sampler = (wid < 9);              // tids 0..575 <=> ps 0..143
    const int ps = tid >> 2, cg = tid & 3;
    const int qa = ((lane >> 4) ^ ((lane >> 1) & 3)) * 8;
    const int qs = (cg ^ ((ps >> 1) & 3)) * 8;
    const f16* xb = x16 + (size_t)imgb * Cc;
    const int wlo = (tid >> 2) * Cc + ((tid & 3) ^ ((tid >> 3) & 3)) * 8;
    const int wds = tid * 8;
    // sampler pixel coords (valid for tid<576)
    const int hwp = p0 + ps - imgb;
    const int hp = hwp / Wc, wp_ = hwp - hp * Wc;
    // phase-A A-stage mapping (tids 576..767; tids 576..639 take a 2nd slot)
    const int au0 = tid - 576;
    const int arow0 = au0 >> 3, acb0 = au0 & 7;
    const int ah0 = acb0 >> 2, aq0 = acb0 & 3;
    const int adst0 = arow0 * 32 + ((aq0 ^ ((arow0 >> 1) & 3)) * 8);
    const int arow1 = arow0 + 24;
    const int adst1 = arow1 * 32 + ((aq0 ^ ((arow1 >> 1) & 3)) * 8);

    // ================= PHASE A: offset conv =================
    {
        f32x4 accA[2];
        accA[0] = (f32x4){0.f, 0.f, 0.f, 0.f};
        accA[1] = (f32x4){0.f, 0.f, 0.f, 0.f};
        f16x8 X0, X1;           // single reg pipeline buffer (stage->reissue)

#define PA_LOAD(q) do {                                                        \
    int q_ = (q) > 35 ? 35 : (q);                                              \
    int k2_ = q_ >> 2, cq_ = q_ & 3;                                           \
    int ky_ = k2_ / 3, kx_ = k2_ - ky_ * 3;                                    \
    if (sampler) {                                                             \
        int yy_ = hp + ky_ - 1, xx_ = wp_ + kx_ - 1;                           \
        f16x8 t0_ = {0,0,0,0,0,0,0,0}, t1_ = {0,0,0,0,0,0,0,0};                \
        if (yy_ >= 0 && yy_ < Hc && xx_ >= 0 && xx_ < Wc) {                    \
            const f16* s_ = x16 + ((size_t)(imgb + yy_ * Wc + xx_)) * Cc + cq_ * 64 + cg * 8; \
            t0_ = *(const f16x8*)s_;                                           \
            t1_ = *(const f16x8*)(s_ + 32);                                    \
        }                                                                      \
        X0 = t0_; X1 = t1_;                                                    \
    } else {                                                                   \
        X0 = *(const f16x8*)(woffT + ((size_t)(k2_ * 32 + arow0)) * Cc + cq_ * 64 + acb0 * 8); \
        if (tid < 640)                                                         \
            X1 = *(const f16x8*)(woffT + ((size_t)(k2_ * 32 + arow1)) * Cc + cq_ * 64 + acb0 * 8); \
    }                                                                          \
} while (0)

#define PA_STAGE(nb) do {                                                      \
    if (sampler) {                                                             \
        *(f16x8*)&s_s[nb][0][ps * 32 + qs] = X0;                               \
        *(f16x8*)&s_s[nb][1][ps * 32 + qs] = X1;                               \
    } else {                                                                   \
        *(f16x8*)&s_a[nb][ah0][adst0] = X0;                                    \
        if (tid < 640) *(f16x8*)&s_a[nb][ah0][adst1] = X1;                     \
    }                                                                          \
} while (0)

        PA_LOAD(0);
        PA_STAGE(0);                       // waits phase-0 loads
        PA_LOAD(1);                        // reissue: phase 1 in flight
        asm volatile("s_waitcnt lgkmcnt(0)" ::: "memory"); SB();
        __builtin_amdgcn_s_barrier(); SB();

        for (int p = 0; p < 36; ++p) {
            const int bb = p & 1, nb = bb ^ 1;
            f16x8 af0, af1, bf0, bf1;
            if (sampler) {
                af0 = *(const f16x8*)&s_a[bb][0][((lane & 15)) * 32 + qa];
                af1 = *(const f16x8*)&s_a[bb][0][((16 + (lane & 15))) * 32 + qa];
                bf0 = *(const f16x8*)&s_s[bb][0][(wid * 16 + (lane & 15)) * 32 + qa];
            }
            // stage X (holds p+1, loaded one full phase ago), reload for p+2
            PA_STAGE(nb);
            PA_LOAD(p + 2);
            if (sampler) {
                accA[0] = __builtin_amdgcn_mfma_f32_16x16x32_f16(af0, bf0, accA[0], 0, 0, 0);
                accA[1] = __builtin_amdgcn_mfma_f32_16x16x32_f16(af1, bf0, accA[1], 0, 0, 0);
                af0 = *(const f16x8*)&s_a[bb][1][((lane & 15)) * 32 + qa];
                af1 = *(const f16x8*)&s_a[bb][1][((16 + (lane & 15))) * 32 + qa];
                bf1 = *(const f16x8*)&s_s[bb][1][(wid * 16 + (lane & 15)) * 32 + qa];
                accA[0] = __builtin_amdgcn_mfma_f32_16x16x32_f16(af0, bf1, accA[0], 0, 0, 0);
                accA[1] = __builtin_amdgcn_mfma_f32_16x16x32_f16(af1, bf1, accA[1], 0, 0, 0);
            }
            asm volatile("s_waitcnt lgkmcnt(0)" ::: "memory"); SB();
            __builtin_amdgcn_s_barrier(); SB();
        }

        // epilogue A: rows 4q..4q+3 -> taps 2q,2q+1 ; rows 16,17 (q==0) -> tap 8
        if (sampler) {
            const int q = lane >> 4;
            const int pxl = wid * 16 + (lane & 15);
            const int hwq = p0 + pxl - imgb;
            const int hq = hwq / Wc, wq = hwq - hq * Wc;
#define STORE_TAP_LDS(kk, offy, offx) do {                                     \
    float py_ = (float)(hq - 1 + (kk) / 3) + (offy);                           \
    float px_ = (float)(wq - 1 + (kk) % 3) + (offx);                           \
    float y0f_ = floorf(py_), x0f_ = floorf(px_);                              \
    float wy_ = py_ - y0f_, wx_ = px_ - x0f_;                                  \
    int iy0_ = (int)y0f_, ix0_ = (int)x0f_;                                    \
    float vy0_ = (y0f_ >= 0.f && y0f_ <= 95.f) ? 1.f : 0.f;                    \
    float vy1_ = (y0f_ + 1.f >= 0.f && y0f_ + 1.f <= 95.f) ? 1.f : 0.f;        \
    float vx0_ = (x0f_ >= 0.f && x0f_ <= 95.f) ? 1.f : 0.f;                    \
    float vx1_ = (x0f_ + 1.f >= 0.f && x0f_ + 1.f <= 95.f) ? 1.f : 0.f;        \
    int cy0_ = clampi(iy0_, 0, 95), cy1_ = clampi(iy0_ + 1, 0, 95);            \
    int cx0_ = clampi(ix0_, 0, 95), cx1_ = clampi(ix0_ + 1, 0, 95);            \
    s_id[kk][pxl] = make_int4(cy0_ * Wc + cx0_, cy0_ * Wc + cx1_,              \
                              cy1_ * Wc + cx0_, cy1_ * Wc + cx1_);             \
    s_wt[kk][pxl] = make_float4((1.f - wy_) * (1.f - wx_) * vy0_ * vx0_,       \
                                (1.f - wy_) * wx_ * vy0_ * vx1_,               \
                                wy_ * (1.f - wx_) * vy1_ * vx0_,               \
                                wy_ * wx_ * vy1_ * vx1_);                      \
} while (0)
            STORE_TAP_LDS(2 * q,     accA[0][0] + b_off[4 * q],
                                     accA[0][1] + b_off[4 * q + 1]);
            STORE_TAP_LDS(2 * q + 1, accA[0][2] + b_off[4 * q + 2],
                                     accA[0][3] + b_off[4 * q + 3]);
            if (q == 0)
                STORE_TAP_LDS(8, accA[1][0] + b_off[16], accA[1][1] + b_off[17]);
#undef STORE_TAP_LDS
        }
        asm volatile("s_waitcnt lgkmcnt(0)" ::: "memory"); SB();
        __builtin_amdgcn_s_barrier(); SB();
    }

    // ================= PHASE B: deform (R20-proven) =================
#define ISSUE_W(kt, cq, h, nb) do {                                            \
    const f16* g0_ = wT2 + wlo + ((size_t)((kt) * 256)) * Cc + (cq) * 64 + (h) * 32; \
    __builtin_amdgcn_global_load_lds(                                          \
        (const __attribute__((address_space(1))) void*)g0_,                    \
        (__attribute__((address_space(3))) void*)&s_w[nb][h][wds], 16, 0, 0);  \
    if (wid >= 8) {                                                            \
        const f16* g1_ = wT2 + wlo + ((size_t)((kt) * 256 + 64)) * Cc + (cq) * 64 + (h) * 32; \
        __builtin_amdgcn_global_load_lds(                                      \
            (const __attribute__((address_space(1))) void*)g1_,                \
            (__attribute__((address_space(3))) void*)&s_w[nb][h][2048 + wds], 16, 0, 0); \
    }                                                                          \
} while (0)

#define ISSUE_C(dst, idv, co) do {                                             \
    (dst)[0] = *(const f16x8*)(xb + (size_t)(idv).x * Cc + (co) + cg * 8);     \
    (dst)[1] = *(const f16x8*)(xb + (size_t)(idv).y * Cc + (co) + cg * 8);     \
    (dst)[2] = *(const f16x8*)(xb + (size_t)(idv).z * Cc + (co) + cg * 8);     \
    (dst)[3] = *(const f16x8*)(xb + (size_t)(idv).w * Cc + (co) + cg * 8);     \
} while (0)

#define BLEND_WRITE(src, wvv, h, nb) do {                                      \
    f16x8 sv_ = (src)[0] * (f16)(wvv).x + (src)[1] * (f16)(wvv).y              \
              + (src)[2] * (f16)(wvv).z + (src)[3] * (f16)(wvv).w;             \
    *(f16x8*)&s_s[nb][h][ps * 32 + qs] = sv_;                                  \
} while (0)

    f32x4 acc[4][3];
#pragma unroll
    for (int mi = 0; mi < 4; ++mi)
#pragma unroll
        for (int ni = 0; ni < 3; ++ni) acc[mi][ni] = (f32x4){0.f, 0.f, 0.f, 0.f};

    f16x8 c4a[4], c4b[4];
    int4 id;
    float4 wv;
    int4 idN;
    float4 wvN;
    if (sampler) {
        id = s_id[0][ps];
        wv = s_wt[0][ps];
    }

    ISSUE_W(0, 0, 0, 0);
    ISSUE_W(0, 0, 1, 0);
    SB();
    if (sampler) {
        ISSUE_C(c4a, id, 0);
        ISSUE_C(c4b, id, 32);
        BLEND_WRITE(c4a, wv, 0, 0);
        BLEND_WRITE(c4b, wv, 1, 0);
        ISSUE_C(c4a, id, 64);
        ISSUE_C(c4b, id, 96);
        asm volatile("s_waitcnt lgkmcnt(0)" ::: "memory"); SB();
        if (wid == 8) {
            asm volatile("s_waitcnt vmcnt(8)" ::: "memory"); SB();
        }
    } else {
        asm volatile("s_waitcnt vmcnt(0)" ::: "memory"); SB();
    }
    __builtin_amdgcn_s_barrier(); SB();

    for (int k = 0; k < 9; ++k) {
        const int kn = (k < 8) ? k + 1 : 8;
#pragma unroll
        for (int ch = 0; ch < 4; ++ch) {
            const int bb = ch & 1, nb = bb ^ 1;
            f16x8 bf0[3], bf1[3];
#pragma unroll
            for (int ni = 0; ni < 3; ++ni) {
                bf0[ni] = *(const f16x8*)&s_s[bb][0][(wp * 48 + ni * 16 + (lane & 15)) * 32 + qa];
                bf1[ni] = *(const f16x8*)&s_s[bb][1][(wp * 48 + ni * 16 + (lane & 15)) * 32 + qa];
            }
            if (sampler) {
                if (ch == 1) {             // LDS read; needed from ch2
                    idN = s_id[kn][ps];
                    wvN = s_wt[kn][ps];
                }
                ISSUE_W((ch == 3) ? kn : k, (ch + 1) & 3, 0, nb);
                ISSUE_W((ch == 3) ? kn : k, (ch + 1) & 3, 1, nb);
                SB();
                {
                    const float4 wvu = (ch == 3) ? wvN : wv;
                    const int4 idu = (ch >= 2) ? idN : id;
                    const int co2 = ((ch + 2) & 3) * 64;
                    BLEND_WRITE(c4a, wvu, 0, nb);
                    ISSUE_C(c4a, idu, co2);
                    BLEND_WRITE(c4b, wvu, 1, nb);
                    ISSUE_C(c4b, idu, co2 + 32);
                }
            } else {
                ISSUE_W((ch == 3) ? kn : k, (ch + 1) & 3, 0, nb);
                ISSUE_W((ch == 3) ? kn : k, (ch + 1) & 3, 1, nb);
                SB();
            }
#pragma unroll
            for (int mi = 0; mi < 4; ++mi) {
                f16x8 af = *(const f16x8*)&s_w[bb][0][(wo * 64 + mi * 16 + (lane & 15)) * 32 + qa];
#pragma unroll
                for (int ni = 0; ni < 3; ++ni)
                    acc[mi][ni] = __builtin_amdgcn_mfma_f32_16x16x32_f16(
                        af, bf0[ni], acc[mi][ni], 0, 0, 0);
            }
#pragma unroll
            for (int mi = 0; mi < 4; ++mi) {
                f16x8 af = *(const f16x8*)&s_w[bb][1][(wo * 64 + mi * 16 + (lane & 15)) * 32 + qa];
#pragma unroll
                for (int ni = 0; ni < 3; ++ni)
                    acc[mi][ni] = __builtin_amdgcn_mfma_f32_16x16x32_f16(
                        af, bf1[ni], acc[mi][ni], 0, 0, 0);
            }
            // RACE-FREE POINT: drain own ds_writes + own W-to-LDS before the
            // barrier. Waves 0-8: [W x1-2, C x8] -> vmcnt(8). 9-11: vmcnt(0).
            asm volatile("s_waitcnt lgkmcnt(0)" ::: "memory"); SB();
            if (sampler) {
                asm volatile("s_waitcnt vmcnt(8)" ::: "memory"); SB();
            } else {
                asm volatile("s_waitcnt vmcnt(0)" ::: "memory"); SB();
            }
            __builtin_amdgcn_s_barrier(); SB();
        }
        if (sampler) { id = idN; wv = wvN; }
    }

    // epilogue: ReLU; D row = output = (lane>>4)*4+j, col = pixel = lane&15
    if (!last) {
#pragma unroll
        for (int ni = 0; ni < 3; ++ni) {
            const int p = p0 + wp * 48 + ni * 16 + (lane & 15);
#pragma unroll
            for (int mi = 0; mi < 4; ++mi) {
                const int o0 = wo * 64 + mi * 16 + (lane >> 4) * 4;
                f32x4 v = acc[mi][ni];
                f16x4 h = {(f16)fmaxf(v[0], 0.f), (f16)fmaxf(v[1], 0.f),
                           (f16)fmaxf(v[2], 0.f), (f16)fmaxf(v[3], 0.f)};
                *(f16x4*)&o16[(size_t)p * Cc + o0] = h;
            }
        }
    } else {
        const int bimg = imgb / HW;
#pragma unroll
        for (int ni = 0; ni < 3; ++ni) {
            const int p = p0 + wp * 48 + ni * 16 + (lane & 15);
            const int hwl = p - imgb;
#pragma unroll
            for (int mi = 0; mi < 4; ++mi) {
                const int o0 = wo * 64 + mi * 16 + (lane >> 4) * 4;
#pragma unroll
                for (int j = 0; j < 4; ++j)
                    oN[((size_t)(bimg * Cc + o0 + j)) * HW + hwl] =
                        fmaxf(acc[mi][ni][j], 0.f);
            }
        }
    }
#undef ISSUE_W
#undef ISSUE_C
#undef BLEND_WRITE
#undef PA_LOAD
#undef PA_STAGE
}

extern "C" void kernel_launch(void* const* d_in, const int* in_sizes, int n_in,
                              void* d_out, int out_size, void* d_ws, size_t ws_size,
                              hipStream_t stream)
{
    const float* x0 = (const float*)d_in[0];
    float* out = (float*)d_out;

    f16*   x16a = (f16*)d_ws;                          // PIX*Cc f16
    f16*   x16b = x16a + (size_t)PIX * Cc;             // PIX*Cc f16
    f16*   wT2  = x16b + (size_t)PIX * Cc;             // 3 * CK*Cc f16
    f16*   woffT = wT2 + (size_t)3 * CK * Cc;          // 3 * 9*32*256 f16

    prep_all_kernel<<<2304 + 3 * 2592, 256, 0, stream>>>(
        x0,
        (const float*)d_in[3], (const float*)d_in[1],
        (const float*)d_in[6], (const float*)d_in[4],
        (const float*)d_in[9], (const float*)d_in[7],
        x16a, wT2, woffT);

    const f16* xin = x16a;
    for (int L = 0; L < 3; ++L) {
        const float* b_off = (const float*)d_in[2 + 3 * L];
        const int last = (L == 2);
        f16* xo = (L == 0) ? x16b : x16a;

        fused_layer_kernel<<<PIX / 144, 768, 0, stream>>>(
            xin, wT2 + (size_t)L * CK * Cc, woffT + (size_t)L * 9 * 32 * Cc,
            b_off, xo, out, last);

        xin = xo;
    }
}